// Round 1
// baseline (1090.698 us; speedup 1.0000x reference)
//
#include <hip/hip_runtime.h>
#include <hip/hip_bf16.h>
#include <math.h>

#define N_NODES   100000
#define N_EDGES   1600000
#define IN_FEAT   50
#define HIDDEN    64
#define N_CLASSES 41

// ---------------------------------------------------------------------------
// Scatter 1: agg1[dst] += x[src], feature width 50.  One thread per
// (edge, feat).  80M threads total.
// ---------------------------------------------------------------------------
__global__ __launch_bounds__(256) void scatter1_kernel(
    const float* __restrict__ x, const int* __restrict__ src,
    const int* __restrict__ dst, float* __restrict__ agg1) {
  int idx = blockIdx.x * blockDim.x + threadIdx.x;
  if (idx >= N_EDGES * IN_FEAT) return;
  int e = idx / IN_FEAT;
  int f = idx - e * IN_FEAT;
  int s = src[e];
  int d = dst[e];
  atomicAdd(&agg1[d * IN_FEAT + f], x[s * IN_FEAT + f]);
}

// ---------------------------------------------------------------------------
// Layer 1 (fused): h = relu(agg1 @ W1_l + x @ W1_r + b1)   [N, 64]
//                  hl = h @ W2_l                           [N, 41]
// One wave per node; lane j owns output feature j.  W1_l/W1_r/W2_l in LDS.
// ---------------------------------------------------------------------------
__global__ __launch_bounds__(256) void layer1_kernel(
    const float* __restrict__ agg1, const float* __restrict__ x,
    const float* __restrict__ W1l, const float* __restrict__ W1r,
    const float* __restrict__ b1, const float* __restrict__ W2l,
    float* __restrict__ h, float* __restrict__ hl) {
  __shared__ float sW1l[IN_FEAT * HIDDEN];   // 12.8 KB
  __shared__ float sW1r[IN_FEAT * HIDDEN];   // 12.8 KB
  __shared__ float sW2l[HIDDEN * N_CLASSES]; // 10.5 KB

  int tid = threadIdx.x;
  for (int i = tid; i < IN_FEAT * HIDDEN; i += 256) {
    sW1l[i] = W1l[i];
    sW1r[i] = W1r[i];
  }
  for (int i = tid; i < HIDDEN * N_CLASSES; i += 256) sW2l[i] = W2l[i];
  __syncthreads();

  int node = (blockIdx.x * blockDim.x + tid) >> 6;   // one wave per node
  if (node >= N_NODES) return;
  int lane = tid & 63;

  const float* arow = agg1 + node * IN_FEAT;
  const float* xrow = x + node * IN_FEAT;
  float acc = b1[lane];
#pragma unroll
  for (int k = 0; k < IN_FEAT; ++k) {
    float a = arow[k];   // wave-uniform broadcast load
    float b = xrow[k];
    acc = fmaf(a, sW1l[k * HIDDEN + lane], acc);
    acc = fmaf(b, sW1r[k * HIDDEN + lane], acc);
  }
  float hval = fmaxf(acc, 0.0f);
  h[node * HIDDEN + lane] = hval;

  // hl = h_row @ W2_l : lane j (<41) accumulates over k via shuffle broadcast
  float acc2 = 0.0f;
#pragma unroll
  for (int k = 0; k < HIDDEN; ++k) {
    float hv = __shfl(hval, k);
    if (lane < N_CLASSES) acc2 = fmaf(hv, sW2l[k * N_CLASSES + lane], acc2);
  }
  if (lane < N_CLASSES) hl[node * N_CLASSES + lane] = acc2;
}

// ---------------------------------------------------------------------------
// Scatter 2: agg2[dst] += hl[src], feature width 41.  65.6M threads.
// ---------------------------------------------------------------------------
__global__ __launch_bounds__(256) void scatter2_kernel(
    const float* __restrict__ hl, const int* __restrict__ src,
    const int* __restrict__ dst, float* __restrict__ agg2) {
  int idx = blockIdx.x * blockDim.x + threadIdx.x;
  if (idx >= N_EDGES * N_CLASSES) return;
  int e = idx / N_CLASSES;
  int f = idx - e * N_CLASSES;
  int s = src[e];
  int d = dst[e];
  atomicAdd(&agg2[d * N_CLASSES + f], hl[s * N_CLASSES + f]);
}

// ---------------------------------------------------------------------------
// Final: o = agg2 + h @ W2_r + b2 ; out = log_softmax(o)   [N, 41]
// One wave per node; lanes 0..40 hold the classes.
// ---------------------------------------------------------------------------
__global__ __launch_bounds__(256) void final_kernel(
    const float* __restrict__ agg2, const float* __restrict__ h,
    const float* __restrict__ W2r, const float* __restrict__ b2,
    float* __restrict__ out) {
  __shared__ float sW2r[HIDDEN * N_CLASSES]; // 10.5 KB
  int tid = threadIdx.x;
  for (int i = tid; i < HIDDEN * N_CLASSES; i += 256) sW2r[i] = W2r[i];
  __syncthreads();

  int node = (blockIdx.x * blockDim.x + tid) >> 6;
  if (node >= N_NODES) return;
  int lane = tid & 63;

  const float* hrow = h + node * HIDDEN;
  float o = 0.0f;
  if (lane < N_CLASSES) {
    o = agg2[node * N_CLASSES + lane] + b2[lane];
#pragma unroll
    for (int k = 0; k < HIDDEN; ++k) {
      o = fmaf(hrow[k], sW2r[k * N_CLASSES + lane], o);
    }
  }

  // wave-wide max over the 41 valid lanes
  float v = (lane < N_CLASSES) ? o : -INFINITY;
#pragma unroll
  for (int off = 32; off >= 1; off >>= 1) v = fmaxf(v, __shfl_xor(v, off));
  // v == row max on all lanes
  float ex = (lane < N_CLASSES) ? expf(o - v) : 0.0f;
  float s = ex;
#pragma unroll
  for (int off = 32; off >= 1; off >>= 1) s += __shfl_xor(s, off);
  float lse = logf(s);
  if (lane < N_CLASSES) out[node * N_CLASSES + lane] = o - v - lse;
}

// ---------------------------------------------------------------------------
extern "C" void kernel_launch(void* const* d_in, const int* in_sizes, int n_in,
                              void* d_out, int out_size, void* d_ws, size_t ws_size,
                              hipStream_t stream) {
  const float* x   = (const float*)d_in[0];
  const float* W1l = (const float*)d_in[1];
  const float* W1r = (const float*)d_in[2];
  const float* b1  = (const float*)d_in[3];
  const float* W2l = (const float*)d_in[4];
  const float* W2r = (const float*)d_in[5];
  const float* b2  = (const float*)d_in[6];
  const int*   src = (const int*)d_in[7];
  const int*   dst = (const int*)d_in[8];
  float* out = (float*)d_out;

  // workspace layout (floats):
  //   agg1 [N*50] | h [N*64] | hl [N*41] | agg2 [N*41]   -> 78.4 MB total
  float* ws   = (float*)d_ws;
  float* agg1 = ws;
  float* h    = agg1 + (size_t)N_NODES * IN_FEAT;
  float* hl   = h    + (size_t)N_NODES * HIDDEN;
  float* agg2 = hl   + (size_t)N_NODES * N_CLASSES;

  hipMemsetAsync(agg1, 0, (size_t)N_NODES * IN_FEAT * sizeof(float), stream);
  hipMemsetAsync(agg2, 0, (size_t)N_NODES * N_CLASSES * sizeof(float), stream);

  {
    int total = N_EDGES * IN_FEAT;
    scatter1_kernel<<<(total + 255) / 256, 256, 0, stream>>>(x, src, dst, agg1);
  }
  {
    int blocks = (N_NODES * 64 + 255) / 256;   // one wave per node
    layer1_kernel<<<blocks, 256, 0, stream>>>(agg1, x, W1l, W1r, b1, W2l, h, hl);
  }
  {
    int total = N_EDGES * N_CLASSES;
    scatter2_kernel<<<(total + 255) / 256, 256, 0, stream>>>(hl, src, dst, agg2);
  }
  {
    int blocks = (N_NODES * 64 + 255) / 256;
    final_kernel<<<blocks, 256, 0, stream>>>(agg2, h, W2r, b2, out);
  }
}

// Round 2
// 861.118 us; speedup vs baseline: 1.2666x; 1.2666x over previous
//
#include <hip/hip_runtime.h>
#include <hip/hip_bf16.h>
#include <math.h>

#define N_NODES   100000
#define N_EDGES   1600000
#define IN_FEAT   50
#define HIDDEN    64
#define N_CLASSES 41

#define SCAN_CHUNK 2048
#define SCAN_NBLK  ((N_NODES + SCAN_CHUNK - 1) / SCAN_CHUNK)   // 49 (<=64)

// ---------------------------------------------------------------------------
// Counting-sort by dst.  Step 1: histogram of dst.
// ---------------------------------------------------------------------------
__global__ __launch_bounds__(256) void hist_kernel(
    const int* __restrict__ dst, int* __restrict__ counts) {
  int e = blockIdx.x * 256 + threadIdx.x;
  if (e < N_EDGES) atomicAdd(&counts[dst[e]], 1);
}

// Step 2a: per-chunk (2048 counts) reduction -> partial[49]
__global__ __launch_bounds__(256) void scanA_kernel(
    const int* __restrict__ counts, int* __restrict__ partial) {
  __shared__ int lds[256];
  int base = blockIdx.x * SCAN_CHUNK;
  int sum = 0;
  for (int i = threadIdx.x; i < SCAN_CHUNK; i += 256) {
    int idx = base + i;
    sum += (idx < N_NODES) ? counts[idx] : 0;
  }
  lds[threadIdx.x] = sum;
  __syncthreads();
  for (int off = 128; off >= 1; off >>= 1) {
    if (threadIdx.x < off) lds[threadIdx.x] += lds[threadIdx.x + off];
    __syncthreads();
  }
  if (threadIdx.x == 0) partial[blockIdx.x] = lds[0];
}

// Step 2b: single-wave exclusive scan of the 49 partials (in place).
__global__ __launch_bounds__(64) void scanB_kernel(
    int* __restrict__ partial, int* __restrict__ start) {
  int lane = threadIdx.x;
  int orig = (lane < SCAN_NBLK) ? partial[lane] : 0;
  int v = orig;
  for (int off = 1; off < 64; off <<= 1) {
    int t = __shfl_up(v, off);
    if (lane >= off) v += t;
  }
  if (lane < SCAN_NBLK) partial[lane] = v - orig;   // exclusive
  if (lane == 0) start[N_NODES] = N_EDGES;
}

// Step 2c: per-chunk exclusive scan + chunk offset -> start[] and cursor[].
__global__ __launch_bounds__(256) void scanC_kernel(
    const int* __restrict__ counts, const int* __restrict__ blockoff,
    int* __restrict__ start, int* __restrict__ cursor) {
  __shared__ int lds[256];
  const int PT = SCAN_CHUNK / 256;                  // 8
  int base = blockIdx.x * SCAN_CHUNK + threadIdx.x * PT;
  int c[PT];
  int tsum = 0;
#pragma unroll
  for (int k = 0; k < PT; ++k) {
    int idx = base + k;
    c[k] = (idx < N_NODES) ? counts[idx] : 0;
    tsum += c[k];
  }
  lds[threadIdx.x] = tsum;
  __syncthreads();
  for (int off = 1; off < 256; off <<= 1) {         // Hillis-Steele inclusive
    int t = (threadIdx.x >= (unsigned)off) ? lds[threadIdx.x - off] : 0;
    __syncthreads();
    lds[threadIdx.x] += t;
    __syncthreads();
  }
  int run = blockoff[blockIdx.x] + lds[threadIdx.x] - tsum;  // exclusive
#pragma unroll
  for (int k = 0; k < PT; ++k) {
    int idx = base + k;
    if (idx < N_NODES) { start[idx] = run; cursor[idx] = run; }
    run += c[k];
  }
}

// Step 3: permute edge sources into dst-grouped order.
__global__ __launch_bounds__(256) void permute_kernel(
    const int* __restrict__ src, const int* __restrict__ dst,
    int* __restrict__ cursor, int* __restrict__ sorted_src) {
  int e = blockIdx.x * 256 + threadIdx.x;
  if (e < N_EDGES) {
    int pos = atomicAdd(&cursor[dst[e]], 1);
    sorted_src[pos] = src[e];
  }
}

// ---------------------------------------------------------------------------
// Fused gather + layer 1: one wave per node.
//   agg = sum_{e: dst=node} x[src[e]]      (registers, lane<50)
//   h   = relu(agg@W1l + x@W1r + b1)       (lane j -> feature j)
//   hl  = h@W2l                            (lane<41)
// ---------------------------------------------------------------------------
__global__ __launch_bounds__(256) void gl1_kernel(
    const float* __restrict__ x, const int* __restrict__ start,
    const int* __restrict__ ssrc,
    const float* __restrict__ W1l, const float* __restrict__ W1r,
    const float* __restrict__ b1, const float* __restrict__ W2l,
    float* __restrict__ h, float* __restrict__ hl) {
  __shared__ float sW1l[IN_FEAT * HIDDEN];    // 12.8 KB
  __shared__ float sW1r[IN_FEAT * HIDDEN];    // 12.8 KB
  __shared__ float sW2l[HIDDEN * N_CLASSES];  // 10.5 KB  -> 36 KB, 4 blk/CU
  int tid = threadIdx.x;
  for (int i = tid; i < IN_FEAT * HIDDEN; i += 256) {
    sW1l[i] = W1l[i];
    sW1r[i] = W1r[i];
  }
  for (int i = tid; i < HIDDEN * N_CLASSES; i += 256) sW2l[i] = W2l[i];
  __syncthreads();

  int node = (blockIdx.x * 256 + tid) >> 6;
  if (node >= N_NODES) return;
  int lane = tid & 63;

  int s0 = start[node], s1 = start[node + 1];
  // 2-way unrolled gather: independent row loads hide L2/L3 latency
  float a0 = 0.f, a1 = 0.f;
  int j = s0;
  for (; j + 1 < s1; j += 2) {
    int sA = ssrc[j];
    int sB = ssrc[j + 1];
    if (lane < IN_FEAT) {
      a0 += x[sA * IN_FEAT + lane];
      a1 += x[sB * IN_FEAT + lane];
    }
  }
  if (j < s1) {
    int sA = ssrc[j];
    if (lane < IN_FEAT) a0 += x[sA * IN_FEAT + lane];
  }
  float aggv = a0 + a1;
  float xv = (lane < IN_FEAT) ? x[node * IN_FEAT + lane] : 0.f;

  float acc = b1[lane];
#pragma unroll
  for (int k = 0; k < IN_FEAT; ++k) {
    acc = fmaf(__shfl(aggv, k), sW1l[k * HIDDEN + lane], acc);
    acc = fmaf(__shfl(xv, k),  sW1r[k * HIDDEN + lane], acc);
  }
  float hval = fmaxf(acc, 0.0f);
  h[node * HIDDEN + lane] = hval;

  float acc2 = 0.0f;
#pragma unroll
  for (int k = 0; k < HIDDEN; ++k) {
    float hv = __shfl(hval, k);
    if (lane < N_CLASSES) acc2 = fmaf(hv, sW2l[k * N_CLASSES + lane], acc2);
  }
  if (lane < N_CLASSES) hl[node * N_CLASSES + lane] = acc2;
}

// ---------------------------------------------------------------------------
// Fused gather + layer 2 + log_softmax: one wave per node.
//   agg2 = sum_{e: dst=node} hl[src[e]]    (lane<41)
//   o    = agg2 + h@W2r + b2 ; out = log_softmax(o)
// ---------------------------------------------------------------------------
__global__ __launch_bounds__(256) void gfin_kernel(
    const float* __restrict__ h, const float* __restrict__ hl,
    const int* __restrict__ start, const int* __restrict__ ssrc,
    const float* __restrict__ W2r, const float* __restrict__ b2,
    float* __restrict__ out) {
  __shared__ float sW2r[HIDDEN * N_CLASSES];  // 10.5 KB
  int tid = threadIdx.x;
  for (int i = tid; i < HIDDEN * N_CLASSES; i += 256) sW2r[i] = W2r[i];
  __syncthreads();

  int node = (blockIdx.x * 256 + tid) >> 6;
  if (node >= N_NODES) return;
  int lane = tid & 63;

  int s0 = start[node], s1 = start[node + 1];
  float a0 = 0.f, a1 = 0.f;
  int j = s0;
  for (; j + 1 < s1; j += 2) {
    int sA = ssrc[j];
    int sB = ssrc[j + 1];
    if (lane < N_CLASSES) {
      a0 += hl[sA * N_CLASSES + lane];
      a1 += hl[sB * N_CLASSES + lane];
    }
  }
  if (j < s1) {
    int sA = ssrc[j];
    if (lane < N_CLASSES) a0 += hl[sA * N_CLASSES + lane];
  }

  float hv = h[node * HIDDEN + lane];
  float o = 0.0f;
  if (lane < N_CLASSES) o = a0 + a1 + b2[lane];
#pragma unroll
  for (int k = 0; k < HIDDEN; ++k) {
    float hk = __shfl(hv, k);
    if (lane < N_CLASSES) o = fmaf(hk, sW2r[k * N_CLASSES + lane], o);
  }

  float v = (lane < N_CLASSES) ? o : -INFINITY;
#pragma unroll
  for (int off = 32; off >= 1; off >>= 1) v = fmaxf(v, __shfl_xor(v, off));
  float ex = (lane < N_CLASSES) ? expf(o - v) : 0.0f;
  float s = ex;
#pragma unroll
  for (int off = 32; off >= 1; off >>= 1) s += __shfl_xor(s, off);
  float lse = logf(s);
  if (lane < N_CLASSES) out[node * N_CLASSES + lane] = o - v - lse;
}

// ---------------------------------------------------------------------------
extern "C" void kernel_launch(void* const* d_in, const int* in_sizes, int n_in,
                              void* d_out, int out_size, void* d_ws, size_t ws_size,
                              hipStream_t stream) {
  const float* x   = (const float*)d_in[0];
  const float* W1l = (const float*)d_in[1];
  const float* W1r = (const float*)d_in[2];
  const float* b1  = (const float*)d_in[3];
  const float* W2l = (const float*)d_in[4];
  const float* W2r = (const float*)d_in[5];
  const float* b2  = (const float*)d_in[6];
  const int*   src = (const int*)d_in[7];
  const int*   dst = (const int*)d_in[8];
  float* out = (float*)d_out;

  // workspace layout:
  //   counts[N] | start[N+1] | cursor[N] | partial[64] | sorted_src[E]
  //   | h[N*64] f32 | hl[N*41] f32           (~49.6 MB total)
  int* counts = (int*)d_ws;
  int* start  = counts + N_NODES;
  int* cursor = start + (N_NODES + 1);
  int* partial = cursor + N_NODES;
  int* ssrc   = partial + 64;
  float* h    = (float*)(ssrc + N_EDGES);
  float* hl   = h + (size_t)N_NODES * HIDDEN;

  hipMemsetAsync(counts, 0, (size_t)N_NODES * sizeof(int), stream);

  hist_kernel<<<(N_EDGES + 255) / 256, 256, 0, stream>>>(dst, counts);
  scanA_kernel<<<SCAN_NBLK, 256, 0, stream>>>(counts, partial);
  scanB_kernel<<<1, 64, 0, stream>>>(partial, start);
  scanC_kernel<<<SCAN_NBLK, 256, 0, stream>>>(counts, partial, start, cursor);
  permute_kernel<<<(N_EDGES + 255) / 256, 256, 0, stream>>>(src, dst, cursor, ssrc);

  int gblocks = (N_NODES * 64 + 255) / 256;   // one wave per node
  gl1_kernel<<<gblocks, 256, 0, stream>>>(x, start, ssrc, W1l, W1r, b1, W2l, h, hl);
  gfin_kernel<<<gblocks, 256, 0, stream>>>(h, hl, start, ssrc, W2r, b2, out);
}

// Round 4
// 753.308 us; speedup vs baseline: 1.4479x; 1.1431x over previous
//
#include <hip/hip_runtime.h>
#include <hip/hip_bf16.h>
#include <math.h>

#define N_NODES   100000
#define N_EDGES   1600000
#define IN_FEAT   50
#define HIDDEN    64
#define N_CLASSES 41

#define SCAN_CHUNK 2048
#define SCAN_NBLK  ((N_NODES + SCAN_CHUNK - 1) / SCAN_CHUNK)   // 49 (<=64)

// ---------------------------------------------------------------------------
// Counting-sort by dst.  Step 1: histogram of dst.
// ---------------------------------------------------------------------------
__global__ __launch_bounds__(256) void hist_kernel(
    const int* __restrict__ dst, int* __restrict__ counts) {
  int e = blockIdx.x * 256 + threadIdx.x;
  if (e < N_EDGES) atomicAdd(&counts[dst[e]], 1);
}

// Step 2a: per-chunk (2048 counts) reduction -> partial[49]
__global__ __launch_bounds__(256) void scanA_kernel(
    const int* __restrict__ counts, int* __restrict__ partial) {
  __shared__ int lds[256];
  int base = blockIdx.x * SCAN_CHUNK;
  int sum = 0;
  for (int i = threadIdx.x; i < SCAN_CHUNK; i += 256) {
    int idx = base + i;
    sum += (idx < N_NODES) ? counts[idx] : 0;
  }
  lds[threadIdx.x] = sum;
  __syncthreads();
  for (int off = 128; off >= 1; off >>= 1) {
    if (threadIdx.x < off) lds[threadIdx.x] += lds[threadIdx.x + off];
    __syncthreads();
  }
  if (threadIdx.x == 0) partial[blockIdx.x] = lds[0];
}

// Step 2b: single-wave exclusive scan of the 49 partials (in place).
__global__ __launch_bounds__(64) void scanB_kernel(
    int* __restrict__ partial, int* __restrict__ start) {
  int lane = threadIdx.x;
  int orig = (lane < SCAN_NBLK) ? partial[lane] : 0;
  int v = orig;
  for (int off = 1; off < 64; off <<= 1) {
    int t = __shfl_up(v, off);
    if (lane >= off) v += t;
  }
  if (lane < SCAN_NBLK) partial[lane] = v - orig;   // exclusive
  if (lane == 0) start[N_NODES] = N_EDGES;
}

// Step 2c: per-chunk exclusive scan + chunk offset -> start[] and cursor[].
__global__ __launch_bounds__(256) void scanC_kernel(
    const int* __restrict__ counts, const int* __restrict__ blockoff,
    int* __restrict__ start, int* __restrict__ cursor) {
  __shared__ int lds[256];
  const int PT = SCAN_CHUNK / 256;                  // 8
  int base = blockIdx.x * SCAN_CHUNK + threadIdx.x * PT;
  int c[PT];
  int tsum = 0;
#pragma unroll
  for (int k = 0; k < PT; ++k) {
    int idx = base + k;
    c[k] = (idx < N_NODES) ? counts[idx] : 0;
    tsum += c[k];
  }
  lds[threadIdx.x] = tsum;
  __syncthreads();
  for (int off = 1; off < 256; off <<= 1) {         // Hillis-Steele inclusive
    int t = (threadIdx.x >= (unsigned)off) ? lds[threadIdx.x - off] : 0;
    __syncthreads();
    lds[threadIdx.x] += t;
    __syncthreads();
  }
  int run = blockoff[blockIdx.x] + lds[threadIdx.x] - tsum;  // exclusive
#pragma unroll
  for (int k = 0; k < PT; ++k) {
    int idx = base + k;
    if (idx < N_NODES) { start[idx] = run; cursor[idx] = run; }
    run += c[k];
  }
}

// Step 3: permute edge sources into dst-grouped order.
__global__ __launch_bounds__(256) void permute_kernel(
    const int* __restrict__ src, const int* __restrict__ dst,
    int* __restrict__ cursor, int* __restrict__ sorted_src) {
  int e = blockIdx.x * 256 + threadIdx.x;
  if (e < N_EDGES) {
    int pos = atomicAdd(&cursor[dst[e]], 1);
    sorted_src[pos] = src[e];
  }
}

// ---------------------------------------------------------------------------
// Fused gather + layer 1: one wave per node.
// MLP-friendly gather: all neighbor indices loaded in ONE coalesced vmem op
// (lanes 0..deg-1), then 8 independent row loads in flight per iteration.
// ---------------------------------------------------------------------------
__global__ __launch_bounds__(256) void gl1_kernel(
    const float* __restrict__ x, const int* __restrict__ start,
    const int* __restrict__ ssrc,
    const float* __restrict__ W1l, const float* __restrict__ W1r,
    const float* __restrict__ b1, const float* __restrict__ W2l,
    float* __restrict__ h, float* __restrict__ hl) {
  __shared__ float sW1l[IN_FEAT * HIDDEN];    // 12.8 KB
  __shared__ float sW1r[IN_FEAT * HIDDEN];    // 12.8 KB
  __shared__ float sW2l[HIDDEN * N_CLASSES];  // 10.5 KB  -> 36 KB, 4 blk/CU
  int tid = threadIdx.x;
  for (int i = tid; i < IN_FEAT * HIDDEN; i += 256) {
    sW1l[i] = W1l[i];
    sW1r[i] = W1r[i];
  }
  for (int i = tid; i < HIDDEN * N_CLASSES; i += 256) sW2l[i] = W2l[i];
  __syncthreads();

  int node = (blockIdx.x * 256 + tid) >> 6;
  if (node >= N_NODES) return;
  int lane = tid & 63;
  bool fOK = (lane < IN_FEAT);

  // own row (independent load, issued early)
  float xv = fOK ? x[node * IN_FEAT + lane] : 0.f;

  int s0 = start[node], s1 = start[node + 1];
  float a0 = 0.f, a1 = 0.f, a2 = 0.f, a3 = 0.f;

  for (int base = s0; base < s1; base += 64) {
    int cnt = s1 - base;
    if (cnt > 64) cnt = 64;
    // one coalesced index load for up to 64 edges
    int idxv = (lane < cnt) ? ssrc[base + lane] : 0;
    int j = 0;
    for (; j + 8 <= cnt; j += 8) {
      int i0 = __shfl(idxv, j + 0);
      int i1 = __shfl(idxv, j + 1);
      int i2 = __shfl(idxv, j + 2);
      int i3 = __shfl(idxv, j + 3);
      int i4 = __shfl(idxv, j + 4);
      int i5 = __shfl(idxv, j + 5);
      int i6 = __shfl(idxv, j + 6);
      int i7 = __shfl(idxv, j + 7);
      if (fOK) {
        // 8 independent row loads in flight
        float v0 = x[i0 * IN_FEAT + lane];
        float v1 = x[i1 * IN_FEAT + lane];
        float v2 = x[i2 * IN_FEAT + lane];
        float v3 = x[i3 * IN_FEAT + lane];
        float v4 = x[i4 * IN_FEAT + lane];
        float v5 = x[i5 * IN_FEAT + lane];
        float v6 = x[i6 * IN_FEAT + lane];
        float v7 = x[i7 * IN_FEAT + lane];
        a0 += v0; a1 += v1; a2 += v2; a3 += v3;
        a0 += v4; a1 += v5; a2 += v6; a3 += v7;
      }
    }
    for (; j < cnt; ++j) {
      int i0 = __shfl(idxv, j);
      if (fOK) a0 += x[i0 * IN_FEAT + lane];
    }
  }
  float aggv = (a0 + a1) + (a2 + a3);

  float acc = b1[lane];
#pragma unroll
  for (int k = 0; k < IN_FEAT; ++k) {
    acc = fmaf(__shfl(aggv, k), sW1l[k * HIDDEN + lane], acc);
    acc = fmaf(__shfl(xv, k),  sW1r[k * HIDDEN + lane], acc);
  }
  float hval = fmaxf(acc, 0.0f);
  h[node * HIDDEN + lane] = hval;

  float acc2 = 0.0f;
#pragma unroll
  for (int k = 0; k < HIDDEN; ++k) {
    float hv = __shfl(hval, k);
    if (lane < N_CLASSES) acc2 = fmaf(hv, sW2l[k * N_CLASSES + lane], acc2);
  }
  if (lane < N_CLASSES) hl[node * N_CLASSES + lane] = acc2;
}

// ---------------------------------------------------------------------------
// Fused gather + layer 2 + log_softmax: one wave per node, same MLP gather.
// ---------------------------------------------------------------------------
__global__ __launch_bounds__(256) void gfin_kernel(
    const float* __restrict__ h, const float* __restrict__ hl,
    const int* __restrict__ start, const int* __restrict__ ssrc,
    const float* __restrict__ W2r, const float* __restrict__ b2,
    float* __restrict__ out) {
  __shared__ float sW2r[HIDDEN * N_CLASSES];  // 10.5 KB
  int tid = threadIdx.x;
  for (int i = tid; i < HIDDEN * N_CLASSES; i += 256) sW2r[i] = W2r[i];
  __syncthreads();

  int node = (blockIdx.x * 256 + tid) >> 6;
  if (node >= N_NODES) return;
  int lane = tid & 63;
  bool cOK = (lane < N_CLASSES);

  float hv = h[node * HIDDEN + lane];   // full-wave load, issued early

  int s0 = start[node], s1 = start[node + 1];
  float a0 = 0.f, a1 = 0.f, a2 = 0.f, a3 = 0.f;

  for (int base = s0; base < s1; base += 64) {
    int cnt = s1 - base;
    if (cnt > 64) cnt = 64;
    int idxv = (lane < cnt) ? ssrc[base + lane] : 0;
    int j = 0;
    for (; j + 8 <= cnt; j += 8) {
      int i0 = __shfl(idxv, j + 0);
      int i1 = __shfl(idxv, j + 1);
      int i2 = __shfl(idxv, j + 2);
      int i3 = __shfl(idxv, j + 3);
      int i4 = __shfl(idxv, j + 4);
      int i5 = __shfl(idxv, j + 5);
      int i6 = __shfl(idxv, j + 6);
      int i7 = __shfl(idxv, j + 7);
      if (cOK) {
        float v0 = hl[i0 * N_CLASSES + lane];
        float v1 = hl[i1 * N_CLASSES + lane];
        float v2 = hl[i2 * N_CLASSES + lane];
        float v3 = hl[i3 * N_CLASSES + lane];
        float v4 = hl[i4 * N_CLASSES + lane];
        float v5 = hl[i5 * N_CLASSES + lane];
        float v6 = hl[i6 * N_CLASSES + lane];
        float v7 = hl[i7 * N_CLASSES + lane];
        a0 += v0; a1 += v1; a2 += v2; a3 += v3;
        a0 += v4; a1 += v5; a2 += v6; a3 += v7;
      }
    }
    for (; j < cnt; ++j) {
      int i0 = __shfl(idxv, j);
      if (cOK) a0 += hl[i0 * N_CLASSES + lane];
    }
  }

  float o = 0.0f;
  if (cOK) o = (a0 + a1) + (a2 + a3) + b2[lane];
#pragma unroll
  for (int k = 0; k < HIDDEN; ++k) {
    float hk = __shfl(hv, k);
    if (cOK) o = fmaf(hk, sW2r[k * N_CLASSES + lane], o);
  }

  float v = cOK ? o : -INFINITY;
#pragma unroll
  for (int off = 32; off >= 1; off >>= 1) v = fmaxf(v, __shfl_xor(v, off));
  float ex = cOK ? expf(o - v) : 0.0f;
  float s = ex;
#pragma unroll
  for (int off = 32; off >= 1; off >>= 1) s += __shfl_xor(s, off);
  float lse = logf(s);
  if (cOK) out[node * N_CLASSES + lane] = o - v - lse;
}

// ---------------------------------------------------------------------------
extern "C" void kernel_launch(void* const* d_in, const int* in_sizes, int n_in,
                              void* d_out, int out_size, void* d_ws, size_t ws_size,
                              hipStream_t stream) {
  const float* x   = (const float*)d_in[0];
  const float* W1l = (const float*)d_in[1];
  const float* W1r = (const float*)d_in[2];
  const float* b1  = (const float*)d_in[3];
  const float* W2l = (const float*)d_in[4];
  const float* W2r = (const float*)d_in[5];
  const float* b2  = (const float*)d_in[6];
  const int*   src = (const int*)d_in[7];
  const int*   dst = (const int*)d_in[8];
  float* out = (float*)d_out;

  // workspace layout:
  //   counts[N] | start[N+1] | cursor[N] | partial[64] | sorted_src[E]
  //   | h[N*64] f32 | hl[N*41] f32           (~49.6 MB total)
  int* counts = (int*)d_ws;
  int* start  = counts + N_NODES;
  int* cursor = start + (N_NODES + 1);
  int* partial = cursor + N_NODES;
  int* ssrc   = partial + 64;
  float* h    = (float*)(ssrc + N_EDGES);
  float* hl   = h + (size_t)N_NODES * HIDDEN;

  hipMemsetAsync(counts, 0, (size_t)N_NODES * sizeof(int), stream);

  hist_kernel<<<(N_EDGES + 255) / 256, 256, 0, stream>>>(dst, counts);
  scanA_kernel<<<SCAN_NBLK, 256, 0, stream>>>(counts, partial);
  scanB_kernel<<<1, 64, 0, stream>>>(partial, start);
  scanC_kernel<<<SCAN_NBLK, 256, 0, stream>>>(counts, partial, start, cursor);
  permute_kernel<<<(N_EDGES + 255) / 256, 256, 0, stream>>>(src, dst, cursor, ssrc);

  int gblocks = (N_NODES * 64 + 255) / 256;   // one wave per node
  gl1_kernel<<<gblocks, 256, 0, stream>>>(x, start, ssrc, W1l, W1r, b1, W2l, h, hl);
  gfin_kernel<<<gblocks, 256, 0, stream>>>(h, hl, start, ssrc, W2r, b2, out);
}

// Round 5
// 645.695 us; speedup vs baseline: 1.6892x; 1.1667x over previous
//
#include <hip/hip_runtime.h>
#include <hip/hip_bf16.h>
#include <math.h>

#define N_NODES   100000
#define N_EDGES   1600000
#define IN_FEAT   50
#define HIDDEN    64
#define N_CLASSES 41

#define SCAN_CHUNK 2048
#define SCAN_NBLK  ((N_NODES + SCAN_CHUNK - 1) / SCAN_CHUNK)   // 49 (<=64)

// bf16-pair packing helpers (RNE rounding; inputs are finite gaussians)
__device__ __forceinline__ unsigned pack_bf16(float a, float b) {
  unsigned ua = __float_as_uint(a), ub = __float_as_uint(b);
  unsigned ra = (ua + 0x7fffu + ((ua >> 16) & 1u)) >> 16;
  unsigned rb = (ub + 0x7fffu + ((ub >> 16) & 1u)) >> 16;
  return (ra & 0xffffu) | (rb << 16);
}
__device__ __forceinline__ float lo_bf(unsigned u) { return __uint_as_float(u << 16); }
__device__ __forceinline__ float hi_bf(unsigned u) { return __uint_as_float(u & 0xffff0000u); }

// ---------------------------------------------------------------------------
// Counting-sort by dst.  Step 1: histogram of dst.
// ---------------------------------------------------------------------------
__global__ __launch_bounds__(256) void hist_kernel(
    const int* __restrict__ dst, int* __restrict__ counts) {
  int e = blockIdx.x * 256 + threadIdx.x;
  if (e < N_EDGES) atomicAdd(&counts[dst[e]], 1);
}

// Step 2a: per-chunk (2048 counts) reduction -> partial[49]
__global__ __launch_bounds__(256) void scanA_kernel(
    const int* __restrict__ counts, int* __restrict__ partial) {
  __shared__ int lds[256];
  int base = blockIdx.x * SCAN_CHUNK;
  int sum = 0;
  for (int i = threadIdx.x; i < SCAN_CHUNK; i += 256) {
    int idx = base + i;
    sum += (idx < N_NODES) ? counts[idx] : 0;
  }
  lds[threadIdx.x] = sum;
  __syncthreads();
  for (int off = 128; off >= 1; off >>= 1) {
    if (threadIdx.x < off) lds[threadIdx.x] += lds[threadIdx.x + off];
    __syncthreads();
  }
  if (threadIdx.x == 0) partial[blockIdx.x] = lds[0];
}

// Step 2b: single-wave exclusive scan of the 49 partials (in place).
__global__ __launch_bounds__(64) void scanB_kernel(
    int* __restrict__ partial, int* __restrict__ start) {
  int lane = threadIdx.x;
  int orig = (lane < SCAN_NBLK) ? partial[lane] : 0;
  int v = orig;
  for (int off = 1; off < 64; off <<= 1) {
    int t = __shfl_up(v, off);
    if (lane >= off) v += t;
  }
  if (lane < SCAN_NBLK) partial[lane] = v - orig;   // exclusive
  if (lane == 0) start[N_NODES] = N_EDGES;
}

// Step 2c: per-chunk exclusive scan + chunk offset -> start[] and cursor[].
__global__ __launch_bounds__(256) void scanC_kernel(
    const int* __restrict__ counts, const int* __restrict__ blockoff,
    int* __restrict__ start, int* __restrict__ cursor) {
  __shared__ int lds[256];
  const int PT = SCAN_CHUNK / 256;                  // 8
  int base = blockIdx.x * SCAN_CHUNK + threadIdx.x * PT;
  int c[PT];
  int tsum = 0;
#pragma unroll
  for (int k = 0; k < PT; ++k) {
    int idx = base + k;
    c[k] = (idx < N_NODES) ? counts[idx] : 0;
    tsum += c[k];
  }
  lds[threadIdx.x] = tsum;
  __syncthreads();
  for (int off = 1; off < 256; off <<= 1) {         // Hillis-Steele inclusive
    int t = (threadIdx.x >= (unsigned)off) ? lds[threadIdx.x - off] : 0;
    __syncthreads();
    lds[threadIdx.x] += t;
    __syncthreads();
  }
  int run = blockoff[blockIdx.x] + lds[threadIdx.x] - tsum;  // exclusive
#pragma unroll
  for (int k = 0; k < PT; ++k) {
    int idx = base + k;
    if (idx < N_NODES) { start[idx] = run; cursor[idx] = run; }
    run += c[k];
  }
}

// Step 3: permute edge sources into dst-grouped order.
__global__ __launch_bounds__(256) void permute_kernel(
    const int* __restrict__ src, const int* __restrict__ dst,
    int* __restrict__ cursor, int* __restrict__ sorted_src) {
  int e = blockIdx.x * 256 + threadIdx.x;
  if (e < N_EDGES) {
    int pos = atomicAdd(&cursor[dst[e]], 1);
    sorted_src[pos] = src[e];
  }
}

// ---------------------------------------------------------------------------
// Fused gather + layer 1: one wave per node.
// Weights staged in LDS as bf16 PAIRS (two k's per dword):
//   - halves LDS footprint: 21 KB/block -> 7 blocks/CU (~87% occupancy)
//   - halves LDS read count in the per-node MLP (164 -> 82 ds_read)
// __launch_bounds__(256,8) pins VGPR<=64 so occupancy is not reg-limited.
// ---------------------------------------------------------------------------
__global__ __launch_bounds__(256, 8) void gl1_kernel(
    const float* __restrict__ x, const int* __restrict__ start,
    const int* __restrict__ ssrc,
    const float* __restrict__ W1l, const float* __restrict__ W1r,
    const float* __restrict__ b1, const float* __restrict__ W2l,
    float* __restrict__ h, float* __restrict__ hl) {
  __shared__ unsigned sW1l[25 * 64];   // 6.25 KB  (k-pairs x 64 cols)
  __shared__ unsigned sW1r[25 * 64];   // 6.25 KB
  __shared__ unsigned sW2l[32 * 64];   // 8 KB (cols padded 41->64)
  int tid = threadIdx.x;
  for (int i = tid; i < 25 * 64; i += 256) {
    int p = i >> 6, c = i & 63;
    sW1l[i] = pack_bf16(W1l[(2 * p) * HIDDEN + c], W1l[(2 * p + 1) * HIDDEN + c]);
    sW1r[i] = pack_bf16(W1r[(2 * p) * HIDDEN + c], W1r[(2 * p + 1) * HIDDEN + c]);
  }
  for (int i = tid; i < 32 * 64; i += 256) {
    int p = i >> 6, c = i & 63;
    float w0 = (c < N_CLASSES) ? W2l[(2 * p) * N_CLASSES + c] : 0.f;
    float w1 = (c < N_CLASSES) ? W2l[(2 * p + 1) * N_CLASSES + c] : 0.f;
    sW2l[i] = pack_bf16(w0, w1);
  }
  __syncthreads();

  int node = (blockIdx.x * 256 + tid) >> 6;
  if (node >= N_NODES) return;
  int lane = tid & 63;
  bool fOK = (lane < IN_FEAT);

  // own row (independent load, issued early)
  float xv = fOK ? x[node * IN_FEAT + lane] : 0.f;

  int s0 = start[node], s1 = start[node + 1];
  float a0 = 0.f, a1 = 0.f, a2 = 0.f, a3 = 0.f;

  for (int base = s0; base < s1; base += 64) {
    int cnt = s1 - base;
    if (cnt > 64) cnt = 64;
    // one coalesced index load for up to 64 edges
    int idxv = (lane < cnt) ? ssrc[base + lane] : 0;
    int j = 0;
    for (; j + 8 <= cnt; j += 8) {
      int i0 = __shfl(idxv, j + 0);
      int i1 = __shfl(idxv, j + 1);
      int i2 = __shfl(idxv, j + 2);
      int i3 = __shfl(idxv, j + 3);
      int i4 = __shfl(idxv, j + 4);
      int i5 = __shfl(idxv, j + 5);
      int i6 = __shfl(idxv, j + 6);
      int i7 = __shfl(idxv, j + 7);
      if (fOK) {
        float v0 = x[i0 * IN_FEAT + lane];
        float v1 = x[i1 * IN_FEAT + lane];
        float v2 = x[i2 * IN_FEAT + lane];
        float v3 = x[i3 * IN_FEAT + lane];
        float v4 = x[i4 * IN_FEAT + lane];
        float v5 = x[i5 * IN_FEAT + lane];
        float v6 = x[i6 * IN_FEAT + lane];
        float v7 = x[i7 * IN_FEAT + lane];
        a0 += v0; a1 += v1; a2 += v2; a3 += v3;
        a0 += v4; a1 += v5; a2 += v6; a3 += v7;
      }
    }
    for (; j < cnt; ++j) {
      int i0 = __shfl(idxv, j);
      if (fOK) a0 += x[i0 * IN_FEAT + lane];
    }
  }
  float aggv = (a0 + a1) + (a2 + a3);

  float acc = b1[lane];
#pragma unroll
  for (int p = 0; p < 25; ++p) {
    unsigned ul = sW1l[p * 64 + lane];
    unsigned ur = sW1r[p * 64 + lane];
    float g0 = __shfl(aggv, 2 * p), g1 = __shfl(aggv, 2 * p + 1);
    float x0 = __shfl(xv, 2 * p),  x1 = __shfl(xv, 2 * p + 1);
    acc = fmaf(g0, lo_bf(ul), acc);
    acc = fmaf(g1, hi_bf(ul), acc);
    acc = fmaf(x0, lo_bf(ur), acc);
    acc = fmaf(x1, hi_bf(ur), acc);
  }
  float hval = fmaxf(acc, 0.0f);
  h[node * HIDDEN + lane] = hval;

  float acc2 = 0.0f;
#pragma unroll
  for (int p = 0; p < 32; ++p) {
    unsigned u = sW2l[p * 64 + lane];
    float h0 = __shfl(hval, 2 * p), h1 = __shfl(hval, 2 * p + 1);
    acc2 = fmaf(h0, lo_bf(u), acc2);
    acc2 = fmaf(h1, hi_bf(u), acc2);
  }
  if (lane < N_CLASSES) hl[node * N_CLASSES + lane] = acc2;
}

// ---------------------------------------------------------------------------
// Fused gather + layer 2 + log_softmax: one wave per node, same structure.
// sW2r bf16-paired: 8 KB LDS -> 8 blocks/CU.
// ---------------------------------------------------------------------------
__global__ __launch_bounds__(256, 8) void gfin_kernel(
    const float* __restrict__ h, const float* __restrict__ hl,
    const int* __restrict__ start, const int* __restrict__ ssrc,
    const float* __restrict__ W2r, const float* __restrict__ b2,
    float* __restrict__ out) {
  __shared__ unsigned sW2r[32 * 64];   // 8 KB (cols padded 41->64)
  int tid = threadIdx.x;
  for (int i = tid; i < 32 * 64; i += 256) {
    int p = i >> 6, c = i & 63;
    float w0 = (c < N_CLASSES) ? W2r[(2 * p) * N_CLASSES + c] : 0.f;
    float w1 = (c < N_CLASSES) ? W2r[(2 * p + 1) * N_CLASSES + c] : 0.f;
    sW2r[i] = pack_bf16(w0, w1);
  }
  __syncthreads();

  int node = (blockIdx.x * 256 + tid) >> 6;
  if (node >= N_NODES) return;
  int lane = tid & 63;
  bool cOK = (lane < N_CLASSES);

  float hv = h[node * HIDDEN + lane];   // full-wave load, issued early

  int s0 = start[node], s1 = start[node + 1];
  float a0 = 0.f, a1 = 0.f, a2 = 0.f, a3 = 0.f;

  for (int base = s0; base < s1; base += 64) {
    int cnt = s1 - base;
    if (cnt > 64) cnt = 64;
    int idxv = (lane < cnt) ? ssrc[base + lane] : 0;
    int j = 0;
    for (; j + 8 <= cnt; j += 8) {
      int i0 = __shfl(idxv, j + 0);
      int i1 = __shfl(idxv, j + 1);
      int i2 = __shfl(idxv, j + 2);
      int i3 = __shfl(idxv, j + 3);
      int i4 = __shfl(idxv, j + 4);
      int i5 = __shfl(idxv, j + 5);
      int i6 = __shfl(idxv, j + 6);
      int i7 = __shfl(idxv, j + 7);
      if (cOK) {
        float v0 = hl[i0 * N_CLASSES + lane];
        float v1 = hl[i1 * N_CLASSES + lane];
        float v2 = hl[i2 * N_CLASSES + lane];
        float v3 = hl[i3 * N_CLASSES + lane];
        float v4 = hl[i4 * N_CLASSES + lane];
        float v5 = hl[i5 * N_CLASSES + lane];
        float v6 = hl[i6 * N_CLASSES + lane];
        float v7 = hl[i7 * N_CLASSES + lane];
        a0 += v0; a1 += v1; a2 += v2; a3 += v3;
        a0 += v4; a1 += v5; a2 += v6; a3 += v7;
      }
    }
    for (; j < cnt; ++j) {
      int i0 = __shfl(idxv, j);
      if (cOK) a0 += hl[i0 * N_CLASSES + lane];
    }
  }

  float o = 0.0f;
  if (cOK) o = (a0 + a1) + (a2 + a3) + b2[lane];
#pragma unroll
  for (int p = 0; p < 32; ++p) {
    unsigned u = sW2r[p * 64 + lane];
    float h0 = __shfl(hv, 2 * p), h1 = __shfl(hv, 2 * p + 1);
    o = fmaf(h0, lo_bf(u), o);
    o = fmaf(h1, hi_bf(u), o);
  }

  float v = cOK ? o : -INFINITY;
#pragma unroll
  for (int off = 32; off >= 1; off >>= 1) v = fmaxf(v, __shfl_xor(v, off));
  float ex = cOK ? expf(o - v) : 0.0f;
  float s = ex;
#pragma unroll
  for (int off = 32; off >= 1; off >>= 1) s += __shfl_xor(s, off);
  float lse = logf(s);
  if (cOK) out[node * N_CLASSES + lane] = o - v - lse;
}

// ---------------------------------------------------------------------------
extern "C" void kernel_launch(void* const* d_in, const int* in_sizes, int n_in,
                              void* d_out, int out_size, void* d_ws, size_t ws_size,
                              hipStream_t stream) {
  const float* x   = (const float*)d_in[0];
  const float* W1l = (const float*)d_in[1];
  const float* W1r = (const float*)d_in[2];
  const float* b1  = (const float*)d_in[3];
  const float* W2l = (const float*)d_in[4];
  const float* W2r = (const float*)d_in[5];
  const float* b2  = (const float*)d_in[6];
  const int*   src = (const int*)d_in[7];
  const int*   dst = (const int*)d_in[8];
  float* out = (float*)d_out;

  // workspace layout:
  //   counts[N] | start[N+1] | cursor[N] | partial[64] | sorted_src[E]
  //   | h[N*64] f32 | hl[N*41] f32           (~49.6 MB total)
  int* counts = (int*)d_ws;
  int* start  = counts + N_NODES;
  int* cursor = start + (N_NODES + 1);
  int* partial = cursor + N_NODES;
  int* ssrc   = partial + 64;
  float* h    = (float*)(ssrc + N_EDGES);
  float* hl   = h + (size_t)N_NODES * HIDDEN;

  hipMemsetAsync(counts, 0, (size_t)N_NODES * sizeof(int), stream);

  hist_kernel<<<(N_EDGES + 255) / 256, 256, 0, stream>>>(dst, counts);
  scanA_kernel<<<SCAN_NBLK, 256, 0, stream>>>(counts, partial);
  scanB_kernel<<<1, 64, 0, stream>>>(partial, start);
  scanC_kernel<<<SCAN_NBLK, 256, 0, stream>>>(counts, partial, start, cursor);
  permute_kernel<<<(N_EDGES + 255) / 256, 256, 0, stream>>>(src, dst, cursor, ssrc);

  int gblocks = (N_NODES * 64 + 255) / 256;   // one wave per node
  gl1_kernel<<<gblocks, 256, 0, stream>>>(x, start, ssrc, W1l, W1r, b1, W2l, h, hl);
  gfin_kernel<<<gblocks, 256, 0, stream>>>(h, hl, start, ssrc, W2r, b2, out);
}